// Round 1
// baseline (2097.846 us; speedup 1.0000x reference)
//
#include <hip/hip_runtime.h>
#include <stdint.h>

namespace {
constexpr int kB = 64, kT = 4096, kDin = 64, kDe = 24, kH = 128;
constexpr int kCh = 16;                 // steps per pre-chunk
constexpr int kNCh = kT / kCh;          // 256 chunks
constexpr int kRowU = 16;               // uints per padded e row (24 f16 + 8 zero)

typedef __attribute__((ext_vector_type(8))) _Float16 frag8;   // f16 MFMA A/B
typedef __attribute__((ext_vector_type(4))) float v4f;        // MFMA C/D
typedef __attribute__((ext_vector_type(8))) int v8i;          // fp8 MFMA A/B
union H2U { uint32_t u; _Float16 s[2]; };

__device__ __forceinline__ float rcp_fast(float x){
#if __has_builtin(__builtin_amdgcn_rcpf)
  return __builtin_amdgcn_rcpf(x);
#else
  return 1.0f / x;
#endif
}
__device__ __forceinline__ float sigmoid_f(float x){
  return rcp_fast(1.0f + __expf(-x));
}
__device__ __forceinline__ float tanh_f(float x){
  return 1.0f - 2.0f * rcp_fast(1.0f + __expf(2.0f * x));
}
__device__ __forceinline__ uint32_t pack2(float lo, float hi){
  H2U u; u.s[0] = (_Float16)lo; u.s[1] = (_Float16)hi; return u.u;
}
__device__ __forceinline__ uint32_t sw_fp8(float x){   // fallback e4m3 encode
  union{float f; uint32_t u;} v; v.f = x;
  uint32_t s = (v.u >> 24) & 0x80u;
  float a = fabsf(x);
  if (a < 0.0009765625f) return s;
  if (a > 448.0f) a = 448.0f;
  int e; float m = frexpf(a, &e);
  int E = e - 1 + 7;
  uint32_t bits;
  if (E <= 0){
    int q = (int)(a * 512.0f + 0.5f); if (q > 7) q = 7; bits = (uint32_t)q;
  } else {
    int q = (int)(m * 16.0f + 0.5f);
    if (q == 16){ q = 8; ++E; }
    if (E > 15) { E = 15; q = 14; }
    bits = ((uint32_t)E << 3) | ((uint32_t)q & 7u);
  }
  return s | bits;
}
template <bool HI>
__device__ __forceinline__ uint32_t fp8pair(float a, float b, uint32_t old){
#if __has_builtin(__builtin_amdgcn_cvt_pk_fp8_f32)
  return (uint32_t)__builtin_amdgcn_cvt_pk_fp8_f32(a, b, (int)old, HI);
#else
  uint32_t p = sw_fp8(a) | (sw_fp8(b) << 8);
  return HI ? ((old & 0x0000ffffu) | (p << 16)) : ((old & 0xffff0000u) | p);
#endif
}
} // namespace

// Kernel 1 (parallel): e[b,t,:] = sigmoid(x[b,t,:] @ W_emb + b_emb), packed f16,
// rows padded to 32 f16 (last 8 = 0).
__global__ __launch_bounds__(256) void emb_kernel(
    const float* __restrict__ x, const float* __restrict__ W,
    const float* __restrict__ bias, uint32_t* __restrict__ e_out)
{
  int r = blockIdx.x * blockDim.x + threadIdx.x;
  if (r >= kB * kT) return;
  const float4* xr = (const float4*)(x + (size_t)r * kDin);
  float acc[kDe];
#pragma unroll
  for (int k = 0; k < kDe; ++k) acc[k] = bias[k];
#pragma unroll 4
  for (int d4 = 0; d4 < kDin / 4; ++d4){
    float4 xv = xr[d4];
    const float* w0 = W + (size_t)(d4 * 4) * kDe;
#pragma unroll
    for (int k = 0; k < kDe; ++k) acc[k] += xv.x * w0[k];
#pragma unroll
    for (int k = 0; k < kDe; ++k) acc[k] += xv.y * w0[kDe + k];
#pragma unroll
    for (int k = 0; k < kDe; ++k) acc[k] += xv.z * w0[2 * kDe + k];
#pragma unroll
    for (int k = 0; k < kDe; ++k) acc[k] += xv.w * w0[3 * kDe + k];
  }
  uint32_t p[12];
#pragma unroll
  for (int k = 0; k < 12; ++k)
    p[k] = pack2(sigmoid_f(acc[2 * k]), sigmoid_f(acc[2 * k + 1]));
  uint4* dst = (uint4*)(e_out + (size_t)r * kRowU);
  dst[0] = make_uint4(p[0], p[1], p[2],  p[3]);
  dst[1] = make_uint4(p[4], p[5], p[6],  p[7]);
  dst[2] = make_uint4(p[8], p[9], p[10], p[11]);
  dst[3] = make_uint4(0u, 0u, 0u, 0u);
}

// Kernel 2: one block (512 thr, 8 waves) per PAIR of batch chains, software-
// pipelined with a deferred-VALU schedule and ONE barrier per step:
//   iter t: [VALU: gates_t from a-regs (+pb) -> c_t,h_t -> fp8 write buf[t&1]]
//           barrier
//           [ds_read h_t (both chains); 8 MFMA -> a-regs for step t+1]
// Lane split: lanes l<32 run chain A's scalar update, l>=32 chain B's (the
// MFMA row-broadcast means every lane holds its unit's gate value), so the
// activation VALU pass is shared between chains. preh stored as f16 (32 KB)
// to fit two chains under the 64 KB static-LDS cap.
__global__ __launch_bounds__(512, 1) void lstm_kernel(
    const uint32_t* __restrict__ e_ws,
    const float* __restrict__ W_f, const float* __restrict__ b_f,
    const float* __restrict__ W_i, const float* __restrict__ b_i,
    const float* __restrict__ W_c, const float* __restrict__ b_c,
    const float* __restrict__ W_o, const float* __restrict__ b_o,
    const float* __restrict__ W_out, const float* __restrict__ b_out,
    float* __restrict__ out)
{
  __shared__ __align__(16) uint32_t preh16[2 * 4 * kH * 8]; // 32 KB [ch][g][u][16 f16]
  __shared__ __align__(16) uint32_t elds[2 * kCh * kRowU];  // 2 KB e chunks (f16)
  __shared__ __align__(64) uint32_t hfp8[4 * 32];           // [ch][parity][128 B fp8]
  __shared__ float red[16];

  const int b0 = blockIdx.x * 2;   // chains A,B = batches b0, b0+1
  const int t0 = threadIdx.x;
  const int w  = t0 >> 6;
  const int l  = t0 & 63;
  const int q  = l >> 4;
  const int cl = l & 15;
  const int u  = w * 16 + cl;      // hidden unit owned
  const int ch = l >> 5;           // chain this lane's scalar path serves (0=A,1=B)

  const float* Wg[4] = {W_f, W_i, W_c, W_o};

  // fp8 B-frags for the h-GEMM (shared by both chains): B[k][n]: n = u,
  // k = q*32 + r*4 + byte, W row = 24 + k, value*64 with E8M0 scale 2^-6 (121).
  v8i B8[4];
#pragma unroll
  for (int g = 0; g < 4; ++g){
#pragma unroll
    for (int r = 0; r < 8; ++r){
      const float* col = Wg[g] + (size_t)(24 + q * 32 + r * 4) * kH + u;
      uint32_t reg = fp8pair<false>(col[0] * 64.0f, col[kH] * 64.0f, 0u);
      reg = fp8pair<true>(col[2 * kH] * 64.0f, col[3 * kH] * 64.0f, reg);
      B8[g][r] = (int)reg;
    }
  }

  // f16 B-frags for the pre-GEMM (e-part, K=32 padded from 24) — shared weights
  frag8 Bp[4];
  float biasC[4] = {b_f[u], b_i[u], b_c[u], b_o[u]};
#pragma unroll
  for (int g = 0; g < 4; ++g){
#pragma unroll
    for (int j = 0; j < 8; ++j){
      int k = q * 8 + j;
      Bp[g][j] = (_Float16)((k < kDe) ? Wg[g][(size_t)k * kH + u] : 0.0f);
    }
  }

  const uint4* e4 = (const uint4*)e_ws;                 // 4 uint4 per (b,t) row
  const int erow  = t0 & 63;
  const size_t ebase = (size_t)(b0 + (t0 >> 6)) * (kT * 4) + erow; // valid t0<128

  // pre-GEMM for one chain: A rows = 16 steps from elds; D packed f16 -> preh16
  auto do_pregemm = [&](int c){
    frag8 Ae = *(const frag8*)&elds[c * (kCh * kRowU) + cl * kRowU + q * 4];
#pragma unroll
    for (int g = 0; g < 4; ++g){
      v4f cc4; cc4[0] = biasC[g]; cc4[1] = biasC[g]; cc4[2] = biasC[g]; cc4[3] = biasC[g];
      v4f d = __builtin_amdgcn_mfma_f32_16x16x32_f16(Ae, Bp[g], cc4, 0, 0, 0);
      uint2 pk; pk.x = pack2(d[0], d[1]); pk.y = pack2(d[2], d[3]);
      *(uint2*)&preh16[((c * 4 + g) * kH + u) * 8 + q * 2] = pk;   // steps q*4..q*4+3
    }
  };

  float pb[4][kCh];   // this lane's chain's pre-activations for the chunk (f32)
  auto unpk = [](uint32_t v, float& a, float& b){
    H2U t; t.u = v; a = (float)t.s[0]; b = (float)t.s[1];
  };
  auto load_pb = [&](){
#pragma unroll
    for (int g = 0; g < 4; ++g){
      const uint4* src = (const uint4*)&preh16[((ch * 4 + g) * kH + u) * 8];
      uint4 lo = src[0], hi = src[1];
      unpk(lo.x, pb[g][0],  pb[g][1]);  unpk(lo.y, pb[g][2],  pb[g][3]);
      unpk(lo.z, pb[g][4],  pb[g][5]);  unpk(lo.w, pb[g][6],  pb[g][7]);
      unpk(hi.x, pb[g][8],  pb[g][9]);  unpk(hi.y, pb[g][10], pb[g][11]);
      unpk(hi.z, pb[g][12], pb[g][13]); unpk(hi.w, pb[g][14], pb[g][15]);
    }
  };

  // startup: commit e chunk 0 for both chains; pre-GEMM; prefetch chunk 1
  uint4 pre4 = make_uint4(0u, 0u, 0u, 0u);
  if (t0 < 128) ((uint4*)elds)[t0] = e4[ebase];
  __syncthreads();
  do_pregemm(0); do_pregemm(1);
  load_pb();
  if (t0 < 128 && kNCh > 1) pre4 = e4[ebase + (size_t)kCh * 4];

  float cst = 0.0f, h_last = 0.0f;
  const v4f zero4 = {0.0f, 0.0f, 0.0f, 0.0f};
  v4f aA0 = zero4, aA1 = zero4, aA2 = zero4, aA3 = zero4;   // h-GEMM pre-acts,
  v4f aB0 = zero4, aB1 = zero4, aB2 = zero4, aB3 = zero4;   // step t (A,B chains)

#pragma unroll 1
  for (int cc = 0; cc < kNCh; ++cc){
#pragma unroll
    for (int s = 0; s < kCh; ++s){
      const int par = s & 1;

      // ---- VALU phase: finish step t = cc*16+s for this lane's chain ----
      float x0 = (ch ? aB0[0] : aA0[0]) + pb[0][s];
      float x1 = (ch ? aB1[0] : aA1[0]) + pb[1][s];
      float x2 = (ch ? aB2[0] : aA2[0]) + pb[2][s];
      float x3 = (ch ? aB3[0] : aA3[0]) + pb[3][s];
      float f  = sigmoid_f(x0);
      float ig = sigmoid_f(x1);
      float gg = tanh_f(x2);
      float og = sigmoid_f(x3);
      cst    = fmaf(cst, f, ig * gg);
      h_last = tanh_f(cst) * og;
      if (!(l & 16)){   // q==0 writes chain A, q==2 writes chain B
        uint32_t byte = fp8pair<false>(h_last * 64.0f, h_last * 64.0f, 0u) & 0xffu;
        ((uint8_t*)hfp8)[(ch * 2 + par) * 128 + u] = (uint8_t)byte;
      }
      // last step of chunk: commit prefetched e before the barrier
      if (s == kCh - 1 && cc + 1 < kNCh && t0 < 128) ((uint4*)elds)[t0] = pre4;
      __syncthreads();

      // ---- MFMA phase: pre-acts for step t+1, consumed next iteration ----
      v8i Aa = *(const v8i*)&hfp8[(0 + par) * 32 + q * 8];
      v8i Ab = *(const v8i*)&hfp8[(2 + par) * 32 + q * 8];
      aA0 = __builtin_amdgcn_mfma_scale_f32_16x16x128_f8f6f4(
                Aa, B8[0], zero4, 0, 0, 0, 121, 0, 121);
      aA1 = __builtin_amdgcn_mfma_scale_f32_16x16x128_f8f6f4(
                Aa, B8[1], zero4, 0, 0, 0, 121, 0, 121);
      aA2 = __builtin_amdgcn_mfma_scale_f32_16x16x128_f8f6f4(
                Aa, B8[2], zero4, 0, 0, 0, 121, 0, 121);
      aA3 = __builtin_amdgcn_mfma_scale_f32_16x16x128_f8f6f4(
                Aa, B8[3], zero4, 0, 0, 0, 121, 0, 121);
      aB0 = __builtin_amdgcn_mfma_scale_f32_16x16x128_f8f6f4(
                Ab, B8[0], zero4, 0, 0, 0, 121, 0, 121);
      aB1 = __builtin_amdgcn_mfma_scale_f32_16x16x128_f8f6f4(
                Ab, B8[1], zero4, 0, 0, 0, 121, 0, 121);
      aB2 = __builtin_amdgcn_mfma_scale_f32_16x16x128_f8f6f4(
                Ab, B8[2], zero4, 0, 0, 0, 121, 0, 121);
      aB3 = __builtin_amdgcn_mfma_scale_f32_16x16x128_f8f6f4(
                Ab, B8[3], zero4, 0, 0, 0, 121, 0, 121);
    }

    if (cc + 1 < kNCh){
      do_pregemm(0); do_pregemm(1);   // reads elds (barriered), writes preh16
      load_pb();                      // intra-wave, lgkmcnt only
      if (t0 < 128 && cc + 2 < kNCh)
        pre4 = e4[ebase + (size_t)(cc + 2) * kCh * 4];
    }
  }

  // epilogue: out[b] = sigmoid(h_T @ W_out + b_out), per chain.
  // Lanes 0..31 hold chain A state (q0 valid), 32..63 chain B (q2 valid).
  float partial = (!(l & 16)) ? h_last * W_out[u] : 0.0f;
#pragma unroll
  for (int off = 1; off <= 16; off <<= 1) partial += __shfl_xor(partial, off, 64);
  if (l == 0)  red[w]     = partial;          // chain A wave-partials
  if (l == 32) red[8 + w] = partial;          // chain B wave-partials
  __syncthreads();
  if (t0 == 0){
    float acc = b_out[0];
#pragma unroll
    for (int k = 0; k < 8; ++k) acc += red[k];
    out[b0] = sigmoid_f(acc);
  }
  if (t0 == 1){
    float acc = b_out[0];
#pragma unroll
    for (int k = 0; k < 8; ++k) acc += red[8 + k];
    out[b0 + 1] = sigmoid_f(acc);
  }
}

extern "C" void kernel_launch(void* const* d_in, const int* in_sizes, int n_in,
                              void* d_out, int out_size, void* d_ws, size_t ws_size,
                              hipStream_t stream){
  const float* x     = (const float*)d_in[0];
  const float* W_emb = (const float*)d_in[1];
  const float* b_emb = (const float*)d_in[2];
  const float* W_f   = (const float*)d_in[3];
  const float* b_f   = (const float*)d_in[4];
  const float* W_i   = (const float*)d_in[5];
  const float* b_i   = (const float*)d_in[6];
  const float* W_c   = (const float*)d_in[7];
  const float* b_c   = (const float*)d_in[8];
  const float* W_o   = (const float*)d_in[9];
  const float* b_o   = (const float*)d_in[10];
  const float* W_out = (const float*)d_in[11];
  const float* b_out = (const float*)d_in[12];
  float* out = (float*)d_out;
  uint32_t* e_ws = (uint32_t*)d_ws;    // B*T*16*4 = 16.8 MB

  const int rows = kB * kT;
  emb_kernel<<<(rows + 255) / 256, 256, 0, stream>>>(x, W_emb, b_emb, e_ws);
  lstm_kernel<<<kB / 2, 512, 0, stream>>>(e_ws, W_f, b_f, W_i, b_i, W_c, b_c,
                                          W_o, b_o, W_out, b_out, out);
}

// Round 2
// 1463.925 us; speedup vs baseline: 1.4330x; 1.4330x over previous
//
#include <hip/hip_runtime.h>
#include <stdint.h>

namespace {
constexpr int kB = 64, kT = 4096, kDin = 64, kDe = 24, kH = 128;
constexpr int kCh = 16;                 // steps per pre-chunk
constexpr int kNCh = kT / kCh;          // 256 chunks
constexpr int kRowU = 16;               // uints per padded e row (24 f16 + 8 zero)
constexpr int kPS = 20;                 // preh stride per (g,u) in floats (pad 16->20)
constexpr float kLog2e = 1.4426950408889634f;

typedef __attribute__((ext_vector_type(8))) _Float16 frag8;   // f16 MFMA A/B
typedef __attribute__((ext_vector_type(4))) float v4f;        // MFMA C/D
typedef __attribute__((ext_vector_type(8))) int v8i;          // fp8 MFMA A/B
union H2U { uint32_t u; _Float16 s[2]; };

__device__ __forceinline__ float rcp_fast(float x){
#if __has_builtin(__builtin_amdgcn_rcpf)
  return __builtin_amdgcn_rcpf(x);
#else
  return 1.0f / x;
#endif
}
__device__ __forceinline__ float exp2_f(float x){
#if __has_builtin(__builtin_amdgcn_exp2f)
  return __builtin_amdgcn_exp2f(x);
#else
  return exp2f(x);
#endif
}
__device__ __forceinline__ float sigmoid_f(float x){
  return rcp_fast(1.0f + __expf(-x));
}
__device__ __forceinline__ uint32_t pack2(float lo, float hi){
  H2U u; u.s[0] = (_Float16)lo; u.s[1] = (_Float16)hi; return u.u;
}
__device__ __forceinline__ uint32_t sw_fp8(float x){   // fallback e4m3 encode
  union{float f; uint32_t u;} v; v.f = x;
  uint32_t s = (v.u >> 24) & 0x80u;
  float a = fabsf(x);
  if (a < 0.0009765625f) return s;
  if (a > 448.0f) a = 448.0f;
  int e; float m = frexpf(a, &e);
  int E = e - 1 + 7;
  uint32_t bits;
  if (E <= 0){
    int q = (int)(a * 512.0f + 0.5f); if (q > 7) q = 7; bits = (uint32_t)q;
  } else {
    int q = (int)(m * 16.0f + 0.5f);
    if (q == 16){ q = 8; ++E; }
    if (E > 15) { E = 15; q = 14; }
    bits = ((uint32_t)E << 3) | ((uint32_t)q & 7u);
  }
  return s | bits;
}
template <bool HI>
__device__ __forceinline__ uint32_t fp8pair(float a, float b, uint32_t old){
#if __has_builtin(__builtin_amdgcn_cvt_pk_fp8_f32)
  return (uint32_t)__builtin_amdgcn_cvt_pk_fp8_f32(a, b, (int)old, HI);
#else
  uint32_t p = sw_fp8(a) | (sw_fp8(b) << 8);
  return HI ? ((old & 0x0000ffffu) | (p << 16)) : ((old & 0xffff0000u) | p);
#endif
}
// Barrier that only drains LDS ops (h-write visibility); the e-prefetch
// global_load stays in flight across barriers (no vmcnt(0) per step).
__device__ __forceinline__ void lgkm_barrier(){
  asm volatile("s_waitcnt lgkmcnt(0)" ::: "memory");
  __builtin_amdgcn_sched_barrier(0);
  __builtin_amdgcn_s_barrier();
  __builtin_amdgcn_sched_barrier(0);
  asm volatile("" ::: "memory");
}
} // namespace

// Kernel 1 (parallel): e[b,t,:] = sigmoid(x[b,t,:] @ W_emb + b_emb), packed f16,
// rows padded to 32 f16 (last 8 = 0).
__global__ __launch_bounds__(256) void emb_kernel(
    const float* __restrict__ x, const float* __restrict__ W,
    const float* __restrict__ bias, uint32_t* __restrict__ e_out)
{
  int r = blockIdx.x * blockDim.x + threadIdx.x;
  if (r >= kB * kT) return;
  const float4* xr = (const float4*)(x + (size_t)r * kDin);
  float acc[kDe];
#pragma unroll
  for (int k = 0; k < kDe; ++k) acc[k] = bias[k];
#pragma unroll 4
  for (int d4 = 0; d4 < kDin / 4; ++d4){
    float4 xv = xr[d4];
    const float* w0 = W + (size_t)(d4 * 4) * kDe;
#pragma unroll
    for (int k = 0; k < kDe; ++k) acc[k] += xv.x * w0[k];
#pragma unroll
    for (int k = 0; k < kDe; ++k) acc[k] += xv.y * w0[kDe + k];
#pragma unroll
    for (int k = 0; k < kDe; ++k) acc[k] += xv.z * w0[2 * kDe + k];
#pragma unroll
    for (int k = 0; k < kDe; ++k) acc[k] += xv.w * w0[3 * kDe + k];
  }
  uint32_t p[12];
#pragma unroll
  for (int k = 0; k < 12; ++k)
    p[k] = pack2(sigmoid_f(acc[2 * k]), sigmoid_f(acc[2 * k + 1]));
  uint4* dst = (uint4*)(e_out + (size_t)r * kRowU);
  dst[0] = make_uint4(p[0], p[1], p[2],  p[3]);
  dst[1] = make_uint4(p[4], p[5], p[6],  p[7]);
  dst[2] = make_uint4(p[8], p[9], p[10], p[11]);
  dst[3] = make_uint4(0u, 0u, 0u, 0u);
}

// Kernel 2: one block (512 thr, 8 waves) per batch chain (reverted to the
// 1-chain structure). New vs the 1428us baseline:
//  (a) gate-per-lane activations: lane (q,cl) evaluates ONLY gate q of unit
//      cl (1 exp+1 rcp instead of 4+4+tanh pair duplicated in every lane);
//      {f,i,g,o} redistributed intra-wave with 4 ds_bpermute (no barrier).
//  (b) weights/biases prescaled by -log2e (W_c by -2log2e) so every gate is
//      the uniform form fmaf(rcp(1+exp2(x')), S, T), (S,T)=(1,0) sigmoid /
//      (2,-1) tanh. Removes per-gate muls and one select layer.
//  (c) per-step barrier is raw s_barrier + lgkmcnt(0) only (no vmcnt drain).
//  (d) pb is 16 regs (own gate only), load_pb is 4 reads not 16.
__global__ __launch_bounds__(512, 1) void lstm_kernel(
    const uint32_t* __restrict__ e_ws,
    const float* __restrict__ W_f, const float* __restrict__ b_f,
    const float* __restrict__ W_i, const float* __restrict__ b_i,
    const float* __restrict__ W_c, const float* __restrict__ b_c,
    const float* __restrict__ W_o, const float* __restrict__ b_o,
    const float* __restrict__ W_out, const float* __restrict__ b_out,
    float* __restrict__ out)
{
  __shared__ __align__(16) float preh[4 * kH * kPS];      // 40 KB [g][u][s pad 20]
  __shared__ __align__(16) uint32_t elds[kCh * kRowU];    // 1 KB e chunk (f16)
  __shared__ __align__(64) uint32_t hfp8[2 * 32];         // 2 x 128 B h (fp8 x64)
  __shared__ float red[8];

  const int b  = blockIdx.x;
  const int t0 = threadIdx.x;
  const int w  = t0 >> 6;
  const int l  = t0 & 63;
  const int q  = l >> 4;
  const int cl = l & 15;
  const int u  = w * 16 + cl;      // hidden unit owned

  const float* Wg[4] = {W_f, W_i, W_c, W_o};
  const float* bgp[4] = {b_f, b_i, b_c, b_o};
  // negative prescale: sigmoid(x) = rcp(1+exp2(-log2e*x)); tanh(x) =
  // 2*rcp(1+exp2(-2log2e*x)) - 1.  Gate order: 0=f 1=i 2=g(tanh) 3=o.
  const float scl[4] = {-kLog2e, -kLog2e, -2.0f * kLog2e, -kLog2e};

  // fp8 B-frags for the h-GEMM: B[k][n]: n = u, k = q*32 + r*4 + byte,
  // W row = 24 + k, stored value = w*64*scl[g] with E8M0 scale 2^-6 (121).
  v8i B8[4];
#pragma unroll
  for (int g = 0; g < 4; ++g){
    const float sc = scl[g] * 64.0f;
#pragma unroll
    for (int r = 0; r < 8; ++r){
      const float* col = Wg[g] + (size_t)(24 + q * 32 + r * 4) * kH + u;
      uint32_t reg = fp8pair<false>(col[0] * sc, col[kH] * sc, 0u);
      reg = fp8pair<true>(col[2 * kH] * sc, col[3 * kH] * sc, reg);
      B8[g][r] = (int)reg;
    }
  }

  // f16 B-frags for the pre-GEMM (e-part, K=32 padded from 24), prescaled
  frag8 Bp[4];
  float biasC[4];
#pragma unroll
  for (int g = 0; g < 4; ++g){
    biasC[g] = bgp[g][u] * scl[g];
#pragma unroll
    for (int j = 0; j < 8; ++j){
      int k = q * 8 + j;
      Bp[g][j] = (_Float16)((k < kDe) ? Wg[g][(size_t)k * kH + u] * scl[g] : 0.0f);
    }
  }

  // gate-per-lane constants: lane's gate = q
  const float Sg = (q == 2) ? 2.0f : 1.0f;
  const float Tg = (q == 2) ? -1.0f : 0.0f;
  const int aF = cl * 4, aI = (16 + cl) * 4, aG = (32 + cl) * 4, aO = (48 + cl) * 4;

  const uint4* e4 = (const uint4*)e_ws;          // 4 uint4 per (b,t) row
  const size_t bbase = (size_t)b * kT * 4;

  // pre-GEMM: A rows = 16 steps from elds; D[step][unit] -> preh[g][u][step]
  auto do_pregemm = [&](){
    frag8 Ae = *(const frag8*)&elds[cl * kRowU + q * 4];  // A[m=cl][k=q*8+j]
#pragma unroll
    for (int g = 0; g < 4; ++g){
      v4f c; c[0] = biasC[g]; c[1] = biasC[g]; c[2] = biasC[g]; c[3] = biasC[g];
      v4f d = __builtin_amdgcn_mfma_f32_16x16x32_f16(Ae, Bp[g], c, 0, 0, 0);
      // lane (q,cl) holds steps q*4+r for unit u -> one aligned b128 write
      *(v4f*)&preh[(g * kH + u) * kPS + q * 4] = d;
    }
  };
  // chunk-wide pre prefetch: own gate only -> 16 f32 regs
  float pb[kCh];
  auto load_pb = [&](){
    const v4f* src = (const v4f*)&preh[(q * kH + u) * kPS];
#pragma unroll
    for (int r = 0; r < 4; ++r){
      v4f t = src[r];
      pb[4*r+0] = t[0]; pb[4*r+1] = t[1]; pb[4*r+2] = t[2]; pb[4*r+3] = t[3];
    }
  };

  // startup: e chunk 0 -> elds; h = 0; pre-GEMM chunk 0; prefetch chunk 1
  uint4 pre4;
  if (t0 < 64) ((uint4*)elds)[t0] = e4[bbase + t0];
  if (t0 < 32) hfp8[t0] = 0u;
  __syncthreads();
  do_pregemm();
  load_pb();
  if (t0 < 64 && kNCh > 1) pre4 = e4[bbase + (size_t)kCh * 4 + t0];

  float cst = 0.0f, h_last = 0.0f;
  const v4f zero4 = {0.0f, 0.0f, 0.0f, 0.0f};

#pragma unroll 1
  for (int cc = 0; cc < kNCh; ++cc){
#pragma unroll
    for (int s = 0; s < kCh; ++s){
      const int cur = (cc * kCh + s) & 1, nxt = cur ^ 1;

      // A: 32 h-bytes for this lane's k-quad, direct v8i LDS load
      v8i A = *(const v8i*)&hfp8[cur * 32 + q * 8];

      v4f a0 = __builtin_amdgcn_mfma_scale_f32_16x16x128_f8f6f4(
                   A, B8[0], zero4, 0, 0, 0, 121, 0, 121);
      v4f a1 = __builtin_amdgcn_mfma_scale_f32_16x16x128_f8f6f4(
                   A, B8[1], zero4, 0, 0, 0, 121, 0, 121);
      v4f a2 = __builtin_amdgcn_mfma_scale_f32_16x16x128_f8f6f4(
                   A, B8[2], zero4, 0, 0, 0, 121, 0, 121);
      v4f a3 = __builtin_amdgcn_mfma_scale_f32_16x16x128_f8f6f4(
                   A, B8[3], zero4, 0, 0, 0, 121, 0, 121);

      // my gate's pre-act (prescaled): select MFMA result by q, add pb
      float t01 = (q == 0) ? a0[0] : a1[0];
      float t23 = (q == 2) ? a2[0] : a3[0];
      float aq  = (q < 2) ? t01 : t23;
      float xg  = aq + pb[s];
      float rr  = rcp_fast(1.0f + exp2_f(xg));
      float gv  = fmaf(rr, Sg, Tg);          // sigmoid or tanh, uniform form

      // redistribute {f,i,g,o} to all lanes (intra-wave crossbar)
      int vi = __float_as_int(gv);
      float fA = __int_as_float(__builtin_amdgcn_ds_bpermute(aF, vi));
      float iA = __int_as_float(__builtin_amdgcn_ds_bpermute(aI, vi));
      float gA = __int_as_float(__builtin_amdgcn_ds_bpermute(aG, vi));
      float oA = __int_as_float(__builtin_amdgcn_ds_bpermute(aO, vi));

      cst = fmaf(cst, fA, iA * gA);
      float rh = rcp_fast(1.0f + exp2_f(-2.0f * kLog2e * cst));
      h_last = fmaf(rh, 2.0f, -1.0f) * oA;   // tanh(cst) * o

      if (l < 16){
        uint32_t byte = fp8pair<false>(h_last * 64.0f, h_last * 64.0f, 0u) & 0xffu;
        ((uint8_t*)&hfp8[nxt * 32])[u] = (uint8_t)byte;
      }
      // last step of chunk: commit prefetched e before the barrier
      if (s == kCh - 1 && cc + 1 < kNCh && t0 < 64) ((uint4*)elds)[t0] = pre4;
      lgkm_barrier();
    }

    if (cc + 1 < kNCh){
      do_pregemm();                // reads elds (barriered), writes preh
      load_pb();                   // intra-wave, lgkmcnt only
      if (t0 < 64 && cc + 2 < kNCh)
        pre4 = e4[bbase + (size_t)(cc + 2) * kCh * 4 + t0];
    }
  }

  // epilogue: out[b] = sigmoid(h_T @ W_out + b_out)
  float partial = (l < 16) ? h_last * W_out[u] : 0.0f;
#pragma unroll
  for (int off = 1; off <= 32; off <<= 1) partial += __shfl_xor(partial, off, 64);
  if (l == 0) red[w] = partial;
  __syncthreads();
  if (t0 == 0){
    float acc = b_out[0];
#pragma unroll
    for (int k = 0; k < 8; ++k) acc += red[k];
    out[b] = sigmoid_f(acc);
  }
}

extern "C" void kernel_launch(void* const* d_in, const int* in_sizes, int n_in,
                              void* d_out, int out_size, void* d_ws, size_t ws_size,
                              hipStream_t stream){
  const float* x     = (const float*)d_in[0];
  const float* W_emb = (const float*)d_in[1];
  const float* b_emb = (const float*)d_in[2];
  const float* W_f   = (const float*)d_in[3];
  const float* b_f   = (const float*)d_in[4];
  const float* W_i   = (const float*)d_in[5];
  const float* b_i   = (const float*)d_in[6];
  const float* W_c   = (const float*)d_in[7];
  const float* b_c   = (const float*)d_in[8];
  const float* W_o   = (const float*)d_in[9];
  const float* b_o   = (const float*)d_in[10];
  const float* W_out = (const float*)d_in[11];
  const float* b_out = (const float*)d_in[12];
  float* out = (float*)d_out;
  uint32_t* e_ws = (uint32_t*)d_ws;    // B*T*16*4 = 16.8 MB

  const int rows = kB * kT;
  emb_kernel<<<(rows + 255) / 256, 256, 0, stream>>>(x, W_emb, b_emb, e_ws);
  lstm_kernel<<<kB, 512, 0, stream>>>(e_ws, W_f, b_f, W_i, b_i, W_c, b_c,
                                      W_o, b_o, W_out, b_out, out);
}

// Round 3
// 1443.865 us; speedup vs baseline: 1.4529x; 1.0139x over previous
//
#include <hip/hip_runtime.h>
#include <stdint.h>

namespace {
constexpr int kB = 64, kT = 4096, kDin = 64, kDe = 24, kH = 128;
constexpr int kCh = 16;                 // steps per pre-chunk
constexpr int kNCh = kT / kCh;          // 256 chunks
constexpr int kRowU = 16;               // uints per padded e row (24 f16 + 8 zero)
constexpr int kPS = 20;                 // preh stride per (g,u) in floats (pad 16->20)
constexpr float kLog2e = 1.4426950408889634f;

typedef __attribute__((ext_vector_type(8))) _Float16 frag8;   // f16 MFMA A/B
typedef __attribute__((ext_vector_type(4))) float v4f;        // MFMA C/D
typedef __attribute__((ext_vector_type(8))) int v8i;          // fp8 MFMA A/B
union H2U { uint32_t u; _Float16 s[2]; };

__device__ __forceinline__ float rcp_fast(float x){
#if __has_builtin(__builtin_amdgcn_rcpf)
  return __builtin_amdgcn_rcpf(x);
#else
  return 1.0f / x;
#endif
}
__device__ __forceinline__ float exp2_f(float x){
#if __has_builtin(__builtin_amdgcn_exp2f)
  return __builtin_amdgcn_exp2f(x);
#else
  return exp2f(x);
#endif
}
__device__ __forceinline__ float sigmoid_f(float x){
  return rcp_fast(1.0f + __expf(-x));
}
__device__ __forceinline__ uint32_t pack2(float lo, float hi){
  H2U u; u.s[0] = (_Float16)lo; u.s[1] = (_Float16)hi; return u.u;
}
__device__ __forceinline__ uint32_t sw_fp8(float x){   // fallback e4m3 encode
  union{float f; uint32_t u;} v; v.f = x;
  uint32_t s = (v.u >> 24) & 0x80u;
  float a = fabsf(x);
  if (a < 0.0009765625f) return s;
  if (a > 448.0f) a = 448.0f;
  int e; float m = frexpf(a, &e);
  int E = e - 1 + 7;
  uint32_t bits;
  if (E <= 0){
    int q = (int)(a * 512.0f + 0.5f); if (q > 7) q = 7; bits = (uint32_t)q;
  } else {
    int q = (int)(m * 16.0f + 0.5f);
    if (q == 16){ q = 8; ++E; }
    if (E > 15) { E = 15; q = 14; }
    bits = ((uint32_t)E << 3) | ((uint32_t)q & 7u);
  }
  return s | bits;
}
template <bool HI>
__device__ __forceinline__ uint32_t fp8pair(float a, float b, uint32_t old){
#if __has_builtin(__builtin_amdgcn_cvt_pk_fp8_f32)
  return (uint32_t)__builtin_amdgcn_cvt_pk_fp8_f32(a, b, (int)old, HI);
#else
  uint32_t p = sw_fp8(a) | (sw_fp8(b) << 8);
  return HI ? ((old & 0x0000ffffu) | (p << 16)) : ((old & 0xffff0000u) | p);
#endif
}
// Barrier that only drains LDS ops (h-write visibility); the e-prefetch
// global_load stays in flight across barriers (no vmcnt(0) per step).
__device__ __forceinline__ void lgkm_barrier(){
  asm volatile("s_waitcnt lgkmcnt(0)" ::: "memory");
  __builtin_amdgcn_sched_barrier(0);
  __builtin_amdgcn_s_barrier();
  __builtin_amdgcn_sched_barrier(0);
  asm volatile("" ::: "memory");
}
} // namespace

// Kernel 1 (parallel): e[b,t,:] = sigmoid(x[b,t,:] @ W_emb + b_emb), packed f16,
// rows padded to 32 f16 (last 8 = 0).
__global__ __launch_bounds__(256) void emb_kernel(
    const float* __restrict__ x, const float* __restrict__ W,
    const float* __restrict__ bias, uint32_t* __restrict__ e_out)
{
  int r = blockIdx.x * blockDim.x + threadIdx.x;
  if (r >= kB * kT) return;
  const float4* xr = (const float4*)(x + (size_t)r * kDin);
  float acc[kDe];
#pragma unroll
  for (int k = 0; k < kDe; ++k) acc[k] = bias[k];
#pragma unroll 4
  for (int d4 = 0; d4 < kDin / 4; ++d4){
    float4 xv = xr[d4];
    const float* w0 = W + (size_t)(d4 * 4) * kDe;
#pragma unroll
    for (int k = 0; k < kDe; ++k) acc[k] += xv.x * w0[k];
#pragma unroll
    for (int k = 0; k < kDe; ++k) acc[k] += xv.y * w0[kDe + k];
#pragma unroll
    for (int k = 0; k < kDe; ++k) acc[k] += xv.z * w0[2 * kDe + k];
#pragma unroll
    for (int k = 0; k < kDe; ++k) acc[k] += xv.w * w0[3 * kDe + k];
  }
  uint32_t p[12];
#pragma unroll
  for (int k = 0; k < 12; ++k)
    p[k] = pack2(sigmoid_f(acc[2 * k]), sigmoid_f(acc[2 * k + 1]));
  uint4* dst = (uint4*)(e_out + (size_t)r * kRowU);
  dst[0] = make_uint4(p[0], p[1], p[2],  p[3]);
  dst[1] = make_uint4(p[4], p[5], p[6],  p[7]);
  dst[2] = make_uint4(p[8], p[9], p[10], p[11]);
  dst[3] = make_uint4(0u, 0u, 0u, 0u);
}

// Kernel 2: one block (512 thr, 8 waves) per batch chain.
// vs round 2 (1369us lstm): the ds_bpermute crossbar is REMOVED from the
// serial chain. The h-GEMM MFMA broadcasts h to all A-rows, so D-rows are
// identical and every lane already holds all four gate pre-acts as
// a0[0],a1[0],a2[0],a3[0] — each lane recomputes f,i,g,o directly (trades
// ~24cy of VALU issue for ~100cy of DS-crossbar latency on the chain).
// Kept from round 2: prescaled weights (uniform rcp(1+exp2(x')) gates),
// lgkm-only per-step barrier. New: fp8 x64 scaling folded into the final
// fma (ho = fma(rh,128,-64)*o = 64*tanh(c)*o), epilogue unscales once.
__global__ __launch_bounds__(512, 1) void lstm_kernel(
    const uint32_t* __restrict__ e_ws,
    const float* __restrict__ W_f, const float* __restrict__ b_f,
    const float* __restrict__ W_i, const float* __restrict__ b_i,
    const float* __restrict__ W_c, const float* __restrict__ b_c,
    const float* __restrict__ W_o, const float* __restrict__ b_o,
    const float* __restrict__ W_out, const float* __restrict__ b_out,
    float* __restrict__ out)
{
  __shared__ __align__(16) float preh[4 * kH * kPS];      // 40 KB [g][u][s pad 20]
  __shared__ __align__(16) uint32_t elds[kCh * kRowU];    // 1 KB e chunk (f16)
  __shared__ __align__(64) uint32_t hfp8[2 * 32];         // 2 x 128 B h (fp8 x64)
  __shared__ float red[8];

  const int b  = blockIdx.x;
  const int t0 = threadIdx.x;
  const int w  = t0 >> 6;
  const int l  = t0 & 63;
  const int q  = l >> 4;
  const int cl = l & 15;
  const int u  = w * 16 + cl;      // hidden unit owned

  const float* Wg[4] = {W_f, W_i, W_c, W_o};
  const float* bgp[4] = {b_f, b_i, b_c, b_o};
  // negative prescale: sigmoid(x) = rcp(1+exp2(-log2e*x)); tanh(x) =
  // 2*rcp(1+exp2(-2log2e*x)) - 1.  Gate order: 0=f 1=i 2=g(tanh) 3=o.
  const float scl[4] = {-kLog2e, -kLog2e, -2.0f * kLog2e, -kLog2e};

  // fp8 B-frags for the h-GEMM: B[k][n]: n = u, k = q*32 + r*4 + byte,
  // W row = 24 + k, stored value = w*64*scl[g] with E8M0 scale 2^-6 (121).
  v8i B8[4];
#pragma unroll
  for (int g = 0; g < 4; ++g){
    const float sc = scl[g] * 64.0f;
#pragma unroll
    for (int r = 0; r < 8; ++r){
      const float* col = Wg[g] + (size_t)(24 + q * 32 + r * 4) * kH + u;
      uint32_t reg = fp8pair<false>(col[0] * sc, col[kH] * sc, 0u);
      reg = fp8pair<true>(col[2 * kH] * sc, col[3 * kH] * sc, reg);
      B8[g][r] = (int)reg;
    }
  }

  // f16 B-frags for the pre-GEMM (e-part, K=32 padded from 24), prescaled
  frag8 Bp[4];
  float biasC[4];
#pragma unroll
  for (int g = 0; g < 4; ++g){
    biasC[g] = bgp[g][u] * scl[g];
#pragma unroll
    for (int j = 0; j < 8; ++j){
      int k = q * 8 + j;
      Bp[g][j] = (_Float16)((k < kDe) ? Wg[g][(size_t)k * kH + u] * scl[g] : 0.0f);
    }
  }

  const uint4* e4 = (const uint4*)e_ws;          // 4 uint4 per (b,t) row
  const size_t bbase = (size_t)b * kT * 4;

  // pre-GEMM: A rows = 16 steps from elds; D[step][unit] -> preh[g][u][step]
  auto do_pregemm = [&](){
    frag8 Ae = *(const frag8*)&elds[cl * kRowU + q * 4];  // A[m=cl][k=q*8+j]
#pragma unroll
    for (int g = 0; g < 4; ++g){
      v4f c; c[0] = biasC[g]; c[1] = biasC[g]; c[2] = biasC[g]; c[3] = biasC[g];
      v4f d = __builtin_amdgcn_mfma_f32_16x16x32_f16(Ae, Bp[g], c, 0, 0, 0);
      // lane (q,cl) holds steps q*4+r for unit u -> one aligned b128 write
      *(v4f*)&preh[(g * kH + u) * kPS + q * 4] = d;
    }
  };
  // chunk-wide pre prefetch: preh[g][u][0..15] -> 16 f32 regs per gate
  float pb[4][kCh];
  auto load_pb = [&](){
#pragma unroll
    for (int g = 0; g < 4; ++g){
      const v4f* src = (const v4f*)&preh[(g * kH + u) * kPS];
#pragma unroll
      for (int r = 0; r < 4; ++r){
        v4f t = src[r];
        pb[g][4*r+0] = t[0]; pb[g][4*r+1] = t[1];
        pb[g][4*r+2] = t[2]; pb[g][4*r+3] = t[3];
      }
    }
  };

  // startup: e chunk 0 -> elds; h = 0; pre-GEMM chunk 0; prefetch chunk 1
  uint4 pre4;
  if (t0 < 64) ((uint4*)elds)[t0] = e4[bbase + t0];
  if (t0 < 32) hfp8[t0] = 0u;
  __syncthreads();
  do_pregemm();
  load_pb();
  if (t0 < 64 && kNCh > 1) pre4 = e4[bbase + (size_t)kCh * 4 + t0];

  float cst = 0.0f, ho = 0.0f;     // ho = 64*tanh(c)*o (fp8-scaled h)
  const v4f zero4 = {0.0f, 0.0f, 0.0f, 0.0f};

#pragma unroll 1
  for (int cc = 0; cc < kNCh; ++cc){
#pragma unroll
    for (int s = 0; s < kCh; ++s){
      const int cur = (cc * kCh + s) & 1, nxt = cur ^ 1;

      // A: 32 h-bytes for this lane's k-quad, direct v8i LDS load
      v8i A = *(const v8i*)&hfp8[cur * 32 + q * 8];

      v4f a0 = __builtin_amdgcn_mfma_scale_f32_16x16x128_f8f6f4(
                   A, B8[0], zero4, 0, 0, 0, 121, 0, 121);
      v4f a1 = __builtin_amdgcn_mfma_scale_f32_16x16x128_f8f6f4(
                   A, B8[1], zero4, 0, 0, 0, 121, 0, 121);
      v4f a2 = __builtin_amdgcn_mfma_scale_f32_16x16x128_f8f6f4(
                   A, B8[2], zero4, 0, 0, 0, 121, 0, 121);
      v4f a3 = __builtin_amdgcn_mfma_scale_f32_16x16x128_f8f6f4(
                   A, B8[3], zero4, 0, 0, 0, 121, 0, 121);

      // all four prescaled gate pre-acts are lane-local (D rows identical)
      float f  = rcp_fast(1.0f + exp2_f(a0[0] + pb[0][s]));
      float ig = rcp_fast(1.0f + exp2_f(a1[0] + pb[1][s]));
      float g2 = rcp_fast(1.0f + exp2_f(a2[0] + pb[2][s]));
      float og = rcp_fast(1.0f + exp2_f(a3[0] + pb[3][s]));
      float gg = fmaf(g2, 2.0f, -1.0f);                   // tanh gate
      cst = fmaf(cst, f, ig * gg);
      float rh = rcp_fast(1.0f + exp2_f(-2.0f * kLog2e * cst));
      ho = fmaf(rh, 128.0f, -64.0f) * og;                 // 64*tanh(c)*o

      if (l < 16){
        uint32_t byte = fp8pair<false>(ho, ho, 0u) & 0xffu;
        ((uint8_t*)&hfp8[nxt * 32])[u] = (uint8_t)byte;
      }
      // last step of chunk: commit prefetched e before the barrier
      if (s == kCh - 1 && cc + 1 < kNCh && t0 < 64) ((uint4*)elds)[t0] = pre4;
      lgkm_barrier();
    }

    if (cc + 1 < kNCh){
      do_pregemm();                // reads elds (barriered), writes preh
      load_pb();                   // intra-wave, lgkmcnt only
      if (t0 < 64 && cc + 2 < kNCh)
        pre4 = e4[bbase + (size_t)(cc + 2) * kCh * 4 + t0];
    }
  }

  // epilogue: out[b] = sigmoid(h_T @ W_out + b_out); h_T = ho/64
  float partial = (l < 16) ? ho * (W_out[u] * 0.015625f) : 0.0f;
#pragma unroll
  for (int off = 1; off <= 32; off <<= 1) partial += __shfl_xor(partial, off, 64);
  if (l == 0) red[w] = partial;
  __syncthreads();
  if (t0 == 0){
    float acc = b_out[0];
#pragma unroll
    for (int k = 0; k < 8; ++k) acc += red[k];
    out[b] = sigmoid_f(acc);
  }
}

extern "C" void kernel_launch(void* const* d_in, const int* in_sizes, int n_in,
                              void* d_out, int out_size, void* d_ws, size_t ws_size,
                              hipStream_t stream){
  const float* x     = (const float*)d_in[0];
  const float* W_emb = (const float*)d_in[1];
  const float* b_emb = (const float*)d_in[2];
  const float* W_f   = (const float*)d_in[3];
  const float* b_f   = (const float*)d_in[4];
  const float* W_i   = (const float*)d_in[5];
  const float* b_i   = (const float*)d_in[6];
  const float* W_c   = (const float*)d_in[7];
  const float* b_c   = (const float*)d_in[8];
  const float* W_o   = (const float*)d_in[9];
  const float* b_o   = (const float*)d_in[10];
  const float* W_out = (const float*)d_in[11];
  const float* b_out = (const float*)d_in[12];
  float* out = (float*)d_out;
  uint32_t* e_ws = (uint32_t*)d_ws;    // B*T*16*4 = 16.8 MB

  const int rows = kB * kT;
  emb_kernel<<<(rows + 255) / 256, 256, 0, stream>>>(x, W_emb, b_emb, e_ws);
  lstm_kernel<<<kB, 512, 0, stream>>>(e_ws, W_f, b_f, W_i, b_i, W_c, b_c,
                                      W_o, b_o, W_out, b_out, out);
}